// Round 5
// baseline (661.433 us; speedup 1.0000x reference)
//
#include <hip/hip_runtime.h>

// ---- problem constants ----
#define DIMQ 2048
#define NHQ  16
#define HDQ  128
#define BQ   2
#define SQ   2048
#define HIDQ 5632
#define MQ   (BQ * SQ)   // 4096
#define SC_ATTN 0.08838834764831845f  // 1/sqrt(128)

using u16 = unsigned short;
using u32 = unsigned int;
typedef __attribute__((ext_vector_type(8))) short s16x8;
typedef __attribute__((ext_vector_type(4))) float f32x4;

__device__ __forceinline__ float bf2f(u16 v) {
  union { u32 u; float f; } w; w.u = ((u32)v) << 16; return w.f;
}
__device__ __forceinline__ u16 f2bf(float f) {
  union { float f; u32 u; } w; w.f = f;
  u32 r = w.u + 0x7FFFu + ((w.u >> 16) & 1u);  // RNE
  return (u16)(r >> 16);
}

__device__ __forceinline__ f32x4 mfma16(s16x8 a, s16x8 b, f32x4 c) {
  return __builtin_amdgcn_mfma_f32_16x16x32_bf16(a, b, c, 0, 0, 0);
}

// async global->LDS, 16B per lane; LDS dest is wave-uniform base + lane*16
__device__ __forceinline__ void gl_lds16(const void* g, void* l) {
  __builtin_amdgcn_global_load_lds((const __attribute__((address_space(1))) void*)g,
                                   (__attribute__((address_space(3))) void*)l,
                                   16, 0, 0);
}

#define SBAR()                                   \
  {                                              \
    asm volatile("" ::: "memory");               \
    __builtin_amdgcn_s_barrier();                \
    asm volatile("" ::: "memory");               \
  }

// ---- weight transpose + fp32->bf16 convert: src[R][Cn] f32 -> dst[Cn][R] bf16 ----
__global__ __launch_bounds__(256) void transpose_cvt(const float* __restrict__ src,
                                                     u16* __restrict__ dst,
                                                     int R, int Cn) {
  __shared__ float tile[32][33];
  const int tx = threadIdx.x, ty = threadIdx.y;
  const int c0 = blockIdx.x * 32, r0 = blockIdx.y * 32;
#pragma unroll
  for (int i = 0; i < 4; ++i)
    tile[ty + i * 8][tx] = src[(size_t)(r0 + ty + i * 8) * Cn + c0 + tx];
  __syncthreads();
#pragma unroll
  for (int i = 0; i < 4; ++i)
    dst[(size_t)(c0 + ty + i * 8) * R + r0 + tx] = f2bf(tile[tx][ty + i * 8]);
}

// ---- V transpose: qkv v-slice [s][d] bf16 -> Vt[bh][d][s] bf16 ----
__global__ __launch_bounds__(256) void vtrans_k(const u16* __restrict__ qkv,
                                                u16* __restrict__ vt) {
  __shared__ u16 tile[32][33];
  const int bh = blockIdx.z;
  const int b = bh >> 4, h = bh & 15;
  const int s0 = blockIdx.x * 32, d0 = blockIdx.y * 32;
  const int tx = threadIdx.x, ty = threadIdx.y;
  const u16* src = qkv + (size_t)(b * SQ) * 6144 + 4096 + h * HDQ;
#pragma unroll
  for (int i = 0; i < 4; ++i)
    tile[ty + i * 8][tx] = src[(size_t)(s0 + ty + i * 8) * 6144 + d0 + tx];
  __syncthreads();
  u16* dst = vt + (size_t)bh * HDQ * SQ;
#pragma unroll
  for (int i = 0; i < 4; ++i)
    dst[(size_t)(d0 + ty + i * 8) * SQ + s0 + tx] = tile[tx][ty + i * 8];
}

// ---- RMSNorm: f32 [rows][2048] -> bf16, one block per row ----
__global__ __launch_bounds__(256) void rmsnorm_k(const float* __restrict__ x,
                                                 const float* __restrict__ w,
                                                 u16* __restrict__ o) {
  const int row = blockIdx.x;
  const int t = threadIdx.x;
  const float* xr = x + (size_t)row * DIMQ;
  const float4 a = ((const float4*)xr)[t * 2];
  const float4 b = ((const float4*)xr)[t * 2 + 1];
  float ss = a.x * a.x + a.y * a.y + a.z * a.z + a.w * a.w +
             b.x * b.x + b.y * b.y + b.z * b.z + b.w * b.w;
#pragma unroll
  for (int off = 32; off > 0; off >>= 1) ss += __shfl_down(ss, off);
  __shared__ float red[4];
  if ((t & 63) == 0) red[t >> 6] = ss;
  __syncthreads();
  ss = red[0] + red[1] + red[2] + red[3];
  const float rs = rsqrtf(ss * (1.0f / (float)DIMQ) + 1e-6f);
  const float4 wa = ((const float4*)w)[t * 2];
  const float4 wb = ((const float4*)w)[t * 2 + 1];
  s16x8 ov;
  ov[0] = (short)f2bf(a.x * rs * wa.x);
  ov[1] = (short)f2bf(a.y * rs * wa.y);
  ov[2] = (short)f2bf(a.z * rs * wa.z);
  ov[3] = (short)f2bf(a.w * rs * wa.w);
  ov[4] = (short)f2bf(b.x * rs * wb.x);
  ov[5] = (short)f2bf(b.y * rs * wb.y);
  ov[6] = (short)f2bf(b.z * rs * wb.z);
  ov[7] = (short)f2bf(b.w * rs * wb.w);
  *(s16x8*)(o + (size_t)row * DIMQ + t * 8) = ov;
}

// ============================================================================
// 256xBN tile GEMM, BK=64, 8 waves (512 thr), 4-phase interleaved schedule:
//  - (row&7)<<4 LDS XOR swizzle, both sides (pre-swizzled global source)
//  - counted vmcnt(4): A(t+2) always in flight across barriers
//  - setprio around MFMA clusters
//  - XCD-chunked, m-fastest block order: each XCD owns an n-column slab so
//    its B panels stay L2-resident; A stays L3-resident chip-wide.
// C[4096][N] = A[4096][K](lda) * Bt[N][K]; OM=0 bf16 out, OM=1 f32 out+resid.
// ============================================================================
template <int OM, int BN>
__global__ __launch_bounds__(512, 1) void gemm256(const u16* __restrict__ A,
                                                  const u16* __restrict__ Bt,
                                                  u16* __restrict__ Cb,
                                                  float* __restrict__ Cf,
                                                  const float* __restrict__ resid,
                                                  int N, int K, int lda) {
  constexpr int BT = BN * 128;             // B K-tile bytes
  constexpr int BLB = BN / 128;            // gl_lds per thread per B half
  constexpr int WNv = (BN == 256) ? 4 : 2; // waves along N
  constexpr int MF = (BN == 256) ? 8 : 4;  // 16-row A frags per wave
  constexpr int MFH = MF / 2;
  __shared__ u16 lds[(65536 + 2 * BT) / 2];  // A: 0,32768; B: 65536, 65536+BT
  const int tid = threadIdx.x, wid = tid >> 6, lane = tid & 63;
  const int wm = wid / WNv, wn = wid % WNv;
  const int r = lane & 15, kc = lane >> 4;
  const int nbx = N / BN;
  const int nwg = nbx << 4;
  // XCD-chunked (blocks o, o+8, ... land on one XCD), m-fastest within chunk:
  // seq = xcd*chunk + local; by = seq%16 (fast), bx = seq/16 (slow).
  const int o = blockIdx.x;
  const int seq = (o & 7) * (nwg >> 3) + (o >> 3);
  const int by = seq & 15, bx = seq >> 4;
  const int m0 = by << 8, n0 = bx * BN;
  const int T = K >> 6;

  const u16* Ag = A + (size_t)m0 * lda;
  const u16* Bg = Bt + (size_t)n0 * K;

  // staging source swizzle (involution byte^=((byte>>7&7)<<4); linear LDS dest)
  const int pl = (tid * 16) ^ (((tid >> 3) & 7) << 4);
  const int prow = pl >> 7;           // = tid>>3, 0..63
  const int pcol = (pl & 127) >> 1;   // element offset within 64-elem row

  // read-side swizzled base: row r, k-chunk kc (XOR ks<<6 per k-slice)
  const int rd0 = r * 128 + ((kc * 16) ^ ((r & 7) << 4));
  const int waveA = wm * (MF * 2048);
  const int waveB = wn * 8192;

  f32x4 acc[MF][4] = {};
  s16x8 af[MFH][2], bfL[2][2], bfH[2][2];

#define STAGE_A(G, kt, BUFB, h)                                                   \
  {                                                                               \
    _Pragma("unroll") for (int i = 0; i < 2; ++i)                                 \
        gl_lds16(G + (size_t)((h) * 128 + i * 64 + prow) * lda + (kt) * 64 + pcol,\
                 (char*)lds + (BUFB) + (h) * 16384 + i * 8192 + (wid << 10));     \
  }
#define STAGE_B(G, kt, BUFB, h)                                                   \
  {                                                                               \
    _Pragma("unroll") for (int i = 0; i < BLB; ++i)                               \
        gl_lds16(G + (size_t)((h) * (BN / 2) + i * 64 + prow) * K + (kt) * 64 + pcol, \
                 (char*)lds + (BUFB) + (h) * (BT / 2) + i * 8192 + (wid << 10));  \
  }

  // prologue: tile0 A+B -> buf0; tile1 A -> buf1
  STAGE_A(Ag, 0, 0, 0);
  STAGE_A(Ag, 0, 0, 1);
  STAGE_B(Bg, 0, 65536, 0);
  STAGE_B(Bg, 0, 65536, 1);
  STAGE_A(Ag, 1, 32768, 0);
  STAGE_A(Ag, 1, 32768, 1);
  asm volatile("s_waitcnt vmcnt(4)" ::: "memory");
  SBAR();

#define TILE_BODY(t, cur)                                                         \
  {                                                                               \
    const int tp1 = ((t) + 1 < T) ? (t) + 1 : T - 1;                              \
    const int tp2 = ((t) + 2 < T) ? (t) + 2 : T - 1;                              \
    const int AB = (cur)*32768;                                                   \
    const int BB = 65536 + (cur)*BT;                                              \
    const int BBn = 65536 + (1 - (cur)) * BT;                                     \
    /* ---- phase 0: stage B.h0(t+1); read A(lo)+B(lo); mfma Q(0,0) ---- */       \
    STAGE_B(Bg, tp1, BBn, 0);                                                     \
    _Pragma("unroll") for (int j = 0; j < MFH; ++j)                               \
        _Pragma("unroll") for (int ks = 0; ks < 2; ++ks)                          \
            af[j][ks] = *(const s16x8*)((const char*)lds + AB + waveA +           \
                                        j * 2048 + (rd0 ^ (ks << 6)));            \
    _Pragma("unroll") for (int n = 0; n < 2; ++n)                                 \
        _Pragma("unroll") for (int ks = 0; ks < 2; ++ks)                          \
            bfL[n][ks] = *(const s16x8*)((const char*)lds + BB + waveB +          \
                                         n * 2048 + (rd0 ^ (ks << 6)));           \
    __builtin_amdgcn_s_setprio(1);                                                \
    _Pragma("unroll") for (int ks = 0; ks < 2; ++ks)                              \
        _Pragma("unroll") for (int j = 0; j < MFH; ++j)                           \
            _Pragma("unroll") for (int n = 0; n < 2; ++n)                         \
                acc[j][n] = mfma16(af[j][ks], bfL[n][ks], acc[j][n]);             \
    __builtin_amdgcn_s_setprio(0);                                                \
    /* ---- phase 1: stage B.h1(t+1); read B(hi); mfma Q(0,1) ---- */             \
    STAGE_B(Bg, tp1, BBn, 1);                                                     \
    _Pragma("unroll") for (int n = 0; n < 2; ++n)                                 \
        _Pragma("unroll") for (int ks = 0; ks < 2; ++ks)                          \
            bfH[n][ks] = *(const s16x8*)((const char*)lds + BB + waveB +          \
                                         (2 + n) * 2048 + (rd0 ^ (ks << 6)));     \
    __builtin_amdgcn_s_setprio(1);                                                \
    _Pragma("unroll") for (int ks = 0; ks < 2; ++ks)                              \
        _Pragma("unroll") for (int j = 0; j < MFH; ++j)                           \
            _Pragma("unroll") for (int n = 0; n < 2; ++n)                         \
                acc[j][2 + n] = mfma16(af[j][ks], bfH[n][ks], acc[j][2 + n]);     \
    __builtin_amdgcn_s_setprio(0);                                                \
    /* ---- phase 2: read A(hi); mfma Q(1,0) ---- */                              \
    _Pragma("unroll") for (int j = 0; j < MFH; ++j)                               \
        _Pragma("unroll") for (int ks = 0; ks < 2; ++ks)                          \
            af[j][ks] = *(const s16x8*)((const char*)lds + AB + waveA +           \
                                        (MFH + j) * 2048 + (rd0 ^ (ks << 6)));    \
    __builtin_amdgcn_s_setprio(1);                                                \
    _Pragma("unroll") for (int ks = 0; ks < 2; ++ks)                              \
        _Pragma("unroll") for (int j = 0; j < MFH; ++j)                           \
            _Pragma("unroll") for (int n = 0; n < 2; ++n)                         \
                acc[MFH + j][n] = mfma16(af[j][ks], bfL[n][ks], acc[MFH + j][n]); \
    __builtin_amdgcn_s_setprio(0);                                                \
    SBAR(); /* all reads of buf[cur] done -> safe to overwrite its A region */    \
    /* ---- phase 3: stage A(t+2) into buf[cur]; mfma Q(1,1) ---- */              \
    STAGE_A(Ag, tp2, AB, 0);                                                      \
    STAGE_A(Ag, tp2, AB, 1);                                                      \
    __builtin_amdgcn_s_setprio(1);                                                \
    _Pragma("unroll") for (int ks = 0; ks < 2; ++ks)                              \
        _Pragma("unroll") for (int j = 0; j < MFH; ++j)                           \
            _Pragma("unroll") for (int n = 0; n < 2; ++n)                         \
                acc[MFH + j][2 + n] = mfma16(af[j][ks], bfH[n][ks], acc[MFH + j][2 + n]); \
    __builtin_amdgcn_s_setprio(0);                                                \
    asm volatile("s_waitcnt vmcnt(4)" ::: "memory"); /* A(t+1)+B(t+1) landed */   \
    SBAR();                                                                       \
  }

  for (int tt = 0; tt < T; tt += 2) {  // T even for all shapes (32, 88)
    TILE_BODY(tt, 0);
    TILE_BODY(tt + 1, 1);
  }
#undef TILE_BODY
#undef STAGE_A
#undef STAGE_B

#pragma unroll
  for (int mf = 0; mf < MF; ++mf)
#pragma unroll
    for (int nf = 0; nf < 4; ++nf)
#pragma unroll
      for (int j = 0; j < 4; ++j) {
        const int rr = m0 + wm * (MF * 16) + mf * 16 + kc * 4 + j;
        const int cc = n0 + wn * 64 + nf * 16 + r;
        const float v = acc[mf][nf][j];
        if (OM == 0) {
          Cb[(size_t)rr * N + cc] = f2bf(v);
        } else {
          Cf[(size_t)rr * N + cc] = v + resid[(size_t)rr * N + cc];
        }
      }
}

// ---- RoPE in-place on q,k halves of qkv [4096][6144] bf16 ----
__global__ __launch_bounds__(256) void rope_k(u16* __restrict__ qkv,
                                              const float* __restrict__ fc,
                                              const float* __restrict__ fs) {
  const int row = blockIdx.x;        // b*S + s
  const int s = row & (SQ - 1);
  const int t = threadIdx.x;
  const int p0 = t * 8;              // first pair handled by this thread
  const int hs = p0 >> 6;            // head-slot 0..31 (q heads then k heads)
  const int i0 = p0 & 63;            // pair index within head, multiple of 8
  u16* base = qkv + (size_t)row * 6144 + hs * HDQ + 2 * i0;
  union { s16x8 v[2]; u16 e[16]; } d;
  d.v[0] = *(const s16x8*)base;
  d.v[1] = *(const s16x8*)(base + 8);
  const float4 c0 = *(const float4*)&fc[(size_t)s * 64 + i0];
  const float4 c1 = *(const float4*)&fc[(size_t)s * 64 + i0 + 4];
  const float4 sn0 = *(const float4*)&fs[(size_t)s * 64 + i0];
  const float4 sn1 = *(const float4*)&fs[(size_t)s * 64 + i0 + 4];
  const float cv[8] = {c0.x, c0.y, c0.z, c0.w, c1.x, c1.y, c1.z, c1.w};
  const float sv[8] = {sn0.x, sn0.y, sn0.z, sn0.w, sn1.x, sn1.y, sn1.z, sn1.w};
#pragma unroll
  for (int k = 0; k < 8; ++k) {
    const float re = bf2f(d.e[2 * k]);
    const float im = bf2f(d.e[2 * k + 1]);
    d.e[2 * k] = f2bf(re * cv[k] - im * sv[k]);
    d.e[2 * k + 1] = f2bf(re * sv[k] + im * cv[k]);
  }
  *(s16x8*)base = d.v[0];
  *(s16x8*)(base + 8) = d.v[1];
}

// ---- causal flash attention. grid (bh=32, qtrev=32), 4 waves, 16 q-rows/wave ----
__global__ __launch_bounds__(256) void attn_k(const u16* __restrict__ qkv,
                                              const u16* __restrict__ vt,
                                              u16* __restrict__ outb) {
  __shared__ u16 Kl[64 * 136];      // [key][d], stride 136
  __shared__ u16 Vl[128 * 72];      // [d][key], stride 72
  __shared__ u16 Pl[4][16 * 80];    // per-wave P tile [qrow][key]
  const int bh = blockIdx.x;
  const int qt = 31 - blockIdx.y;    // heavy blocks dispatched first
  const int b = bh >> 4, h = bh & 15;
  const int q0 = qt * 64;
  const int tid = threadIdx.x, wid = tid >> 6, lane = tid & 63;
  const int r = lane & 15, kc = lane >> 4;
  const size_t base = (size_t)b * SQ * 6144;
  const u16* vtb = vt + (size_t)bh * HDQ * SQ;
  s16x8 qf[4];
  {
    const size_t qoff = base + (size_t)(q0 + wid * 16 + r) * 6144 + h * HDQ;
#pragma unroll
    for (int kk = 0; kk < 4; ++kk)
      qf[kk] = *(const s16x8*)&qkv[qoff + kk * 32 + kc * 8];
  }
  f32x4 acc_o[8] = {};
  float m_run[4], l_run[4];
#pragma unroll
  for (int j = 0; j < 4; ++j) { m_run[j] = -1e30f; l_run[j] = 0.f; }
  const int nt = qt + 1;
  const int skey = tid >> 2, sseg = (tid & 3) * 32;   // K staging: 64 keys x 4 segs
  const int vd = tid >> 1, vseg = (tid & 1) * 32;     // V staging: 128 d x 2 segs
  for (int t = 0; t < nt; ++t) {
    const int kv0 = t * 64;
    __syncthreads();
    {  // stage K [64][136] and V^T [128][72], all b128
      const u16* kg = &qkv[base + (size_t)(kv0 + skey) * 6144 + 2048 + h * HDQ + sseg];
      const u16* vg = &vtb[(size_t)vd * SQ + kv0 + vseg];
#pragma unroll
      for (int jj = 0; jj < 4; ++jj)
        *(s16x8*)&Kl[skey * 136 + sseg + jj * 8] = *(const s16x8*)(kg + jj * 8);
#pragma unroll
      for (int jj = 0; jj < 4; ++jj)
        *(s16x8*)&Vl[vd * 72 + vseg + jj * 8] = *(const s16x8*)(vg + jj * 8);
    }
    __syncthreads();
    // S = Q*K^T for this wave's 16 q-rows x 64 keys
    f32x4 sacc[4] = {};
#pragma unroll
    for (int nf = 0; nf < 4; ++nf)
#pragma unroll
      for (int kk = 0; kk < 4; ++kk) {
        const s16x8 kf = *(const s16x8*)&Kl[(nf * 16 + r) * 136 + kk * 32 + kc * 8];
        sacc[nf] = mfma16(qf[kk], kf, sacc[nf]);
      }
    // online softmax (rows j are spread over 16-lane groups; reduce via shfl_xor)
    float p[4][4], alpha[4];
#pragma unroll
    for (int j = 0; j < 4; ++j) {
      const int qrow = q0 + wid * 16 + kc * 4 + j;
      float svs[4];
      float tm = -1e30f;
#pragma unroll
      for (int nf = 0; nf < 4; ++nf) {
        const int key = kv0 + nf * 16 + r;
        float sv = sacc[nf][j] * SC_ATTN;
        sv = (key > qrow) ? -1e30f : sv;
        svs[nf] = sv;
        tm = fmaxf(tm, sv);
      }
      tm = fmaxf(tm, __shfl_xor(tm, 1));
      tm = fmaxf(tm, __shfl_xor(tm, 2));
      tm = fmaxf(tm, __shfl_xor(tm, 4));
      tm = fmaxf(tm, __shfl_xor(tm, 8));
      const float mnew = fmaxf(m_run[j], tm);
      alpha[j] = __expf(m_run[j] - mnew);
      m_run[j] = mnew;
      float rs = 0.f;
#pragma unroll
      for (int nf = 0; nf < 4; ++nf) {
        const float pv = __expf(svs[nf] - mnew);
        p[nf][j] = pv;
        rs += pv;
      }
      rs += __shfl_xor(rs, 1);
      rs += __shfl_xor(rs, 2);
      rs += __shfl_xor(rs, 4);
      rs += __shfl_xor(rs, 8);
      l_run[j] = l_run[j] * alpha[j] + rs;
    }
#pragma unroll
    for (int nf = 0; nf < 8; ++nf)
#pragma unroll
      for (int j = 0; j < 4; ++j)
        acc_o[nf][j] *= alpha[j];
    // P (D-layout) -> LDS -> A-layout fragments
#pragma unroll
    for (int nf = 0; nf < 4; ++nf)
#pragma unroll
      for (int j = 0; j < 4; ++j)
        Pl[wid][(kc * 4 + j) * 80 + nf * 16 + r] = f2bf(p[nf][j]);
#pragma unroll
    for (int ks = 0; ks < 2; ++ks) {
      const s16x8 pa = *(const s16x8*)&Pl[wid][r * 80 + ks * 32 + kc * 8];
#pragma unroll
      for (int nf = 0; nf < 8; ++nf) {
        const s16x8 bv = *(const s16x8*)&Vl[(nf * 16 + r) * 72 + ks * 32 + kc * 8];
        acc_o[nf] = mfma16(pa, bv, acc_o[nf]);
      }
    }
  }
#pragma unroll
  for (int j = 0; j < 4; ++j) {
    const float inv = 1.0f / l_run[j];
    const size_t orow = (size_t)(b * SQ + q0 + wid * 16 + kc * 4 + j) * DIMQ + h * HDQ;
#pragma unroll
    for (int nf = 0; nf < 8; ++nf)
      outb[orow + nf * 16 + r] = f2bf(acc_o[nf][j] * inv);
  }
}

// ---- silu(gate)*up on merged gu [4096][11264]: cols 0..5631 gate, 5632.. up ----
// writes result in place into the gate slot. grid (11, 4096), block 64.
__global__ __launch_bounds__(64) void silu2_k(u16* __restrict__ gu) {
  const int row = blockIdx.y;
  const int c = (blockIdx.x * 64 + threadIdx.x) * 8;
  u16* gp = gu + (size_t)row * 11264 + c;
  const u16* up = gp + 5632;
  s16x8 gv = *(const s16x8*)gp;
  const s16x8 uv = *(const s16x8*)up;
#pragma unroll
  for (int e = 0; e < 8; ++e) {
    const float fg = bf2f((u16)gv[e]);
    const float fu = bf2f((u16)uv[e]);
    const float sg = fg / (1.f + __expf(-fg));
    gv[e] = (short)f2bf(sg * fu);
  }
  *(s16x8*)gp = gv;
}

extern "C" void kernel_launch(void* const* d_in, const int* in_sizes, int n_in,
                              void* d_out, int out_size, void* d_ws, size_t ws_size,
                              hipStream_t stream) {
  const float* x   = (const float*)d_in[0];
  const float* wq  = (const float*)d_in[1];
  const float* wk  = (const float*)d_in[2];
  const float* wv  = (const float*)d_in[3];
  const float* wo  = (const float*)d_in[4];
  const float* w1  = (const float*)d_in[5];
  const float* w2  = (const float*)d_in[6];  // note: w2 comes before w3 in dict order
  const float* w3  = (const float*)d_in[7];
  const float* anw = (const float*)d_in[8];
  const float* fnw = (const float*)d_in[9];
  const float* fc  = (const float*)d_in[10];
  const float* fs  = (const float*)d_in[11];
  float* out = (float*)d_out;

  char* ws = (char*)d_ws;
  // weights (bf16, transposed [N][K])
  u16* wqkvT = (u16*)(ws);                                  // [6144][2048]
  u16* woT   = (u16*)(ws + 25165824);                       // [2048][2048]
  u16* w13T  = (u16*)(ws + 25165824 + 8388608);             // [11264][2048]
  u16* w2T   = (u16*)(ws + 25165824 + 8388608 + 46137344);  // [2048][5632]
  // activations
  u16* hin   = (u16*)(ws + 102760448);                      // [4096][2048] bf16
  u16* gu    = (u16*)(ws + 119537664);                      // FFN: [4096][11264] bf16 (92.3MB)
  u16* qkvb  = gu;                                          // attn phase: [4096][6144] bf16
  u16* attnb = (u16*)(ws + 119537664 + 50331648);           // [4096][2048] bf16
  u16* vtb   = (u16*)(ws + 119537664 + 50331648 + 16777216);// [32][128][2048] bf16
  float* h = out;                                           // h lives in d_out

  const dim3 tb(32, 8);
  transpose_cvt<<<dim3(64, 64), tb, 0, stream>>>(wq, wqkvT, 2048, 2048);
  transpose_cvt<<<dim3(64, 64), tb, 0, stream>>>(wk, wqkvT + (size_t)2048 * 2048, 2048, 2048);
  transpose_cvt<<<dim3(64, 64), tb, 0, stream>>>(wv, wqkvT + (size_t)2 * 2048 * 2048, 2048, 2048);
  transpose_cvt<<<dim3(64, 64), tb, 0, stream>>>(wo, woT, 2048, 2048);
  transpose_cvt<<<dim3(176, 64), tb, 0, stream>>>(w1, w13T, 2048, 5632);
  transpose_cvt<<<dim3(176, 64), tb, 0, stream>>>(w3, w13T + (size_t)5632 * 2048, 2048, 5632);
  transpose_cvt<<<dim3(64, 176), tb, 0, stream>>>(w2, w2T, 5632, 2048);

  rmsnorm_k<<<4096, 256, 0, stream>>>(x, anw, hin);
  gemm256<0, 128><<<768, 512, 0, stream>>>(hin, wqkvT, qkvb, nullptr, nullptr, 6144, 2048, 2048);
  rope_k<<<4096, 256, 0, stream>>>(qkvb, fc, fs);
  vtrans_k<<<dim3(64, 4, 32), tb, 0, stream>>>(qkvb, vtb);
  attn_k<<<dim3(32, 32), 256, 0, stream>>>(qkvb, vtb, attnb);
  gemm256<1, 128><<<256, 512, 0, stream>>>(attnb, woT, nullptr, h, x, 2048, 2048, 2048);
  rmsnorm_k<<<4096, 256, 0, stream>>>(h, fnw, hin);
  gemm256<0, 256><<<704, 512, 0, stream>>>(hin, w13T, gu, nullptr, nullptr, 11264, 2048, 2048);
  silu2_k<<<dim3(11, 4096), 64, 0, stream>>>(gu);
  gemm256<1, 128><<<256, 512, 0, stream>>>(gu, w2T, nullptr, out, h, 2048, 5632, 11264);
}

// Round 6
// 633.084 us; speedup vs baseline: 1.0448x; 1.0448x over previous
//
#include <hip/hip_runtime.h>

// ---- problem constants ----
#define DIMQ 2048
#define NHQ  16
#define HDQ  128
#define BQ   2
#define SQ   2048
#define HIDQ 5632
#define MQ   (BQ * SQ)   // 4096
#define SC_ATTN 0.08838834764831845f  // 1/sqrt(128)

using u16 = unsigned short;
using u32 = unsigned int;
typedef __attribute__((ext_vector_type(8))) short s16x8;
typedef __attribute__((ext_vector_type(4))) float f32x4;

__device__ __forceinline__ float bf2f(u16 v) {
  union { u32 u; float f; } w; w.u = ((u32)v) << 16; return w.f;
}
__device__ __forceinline__ u16 f2bf(float f) {
  union { float f; u32 u; } w; w.f = f;
  u32 r = w.u + 0x7FFFu + ((w.u >> 16) & 1u);  // RNE
  return (u16)(r >> 16);
}

__device__ __forceinline__ f32x4 mfma16(s16x8 a, s16x8 b, f32x4 c) {
  return __builtin_amdgcn_mfma_f32_16x16x32_bf16(a, b, c, 0, 0, 0);
}

// async global->LDS, 16B per lane; LDS dest is wave-uniform base + lane*16
__device__ __forceinline__ void gl_lds16(const void* g, void* l) {
  __builtin_amdgcn_global_load_lds((const __attribute__((address_space(1))) void*)g,
                                   (__attribute__((address_space(3))) void*)l,
                                   16, 0, 0);
}

#define SBAR()                                   \
  {                                              \
    asm volatile("" ::: "memory");               \
    __builtin_amdgcn_s_barrier();                \
    asm volatile("" ::: "memory");               \
  }

// ---- weight transpose + fp32->bf16 convert: src[R][Cn] f32 -> dst[Cn][R] bf16 ----
__global__ __launch_bounds__(256) void transpose_cvt(const float* __restrict__ src,
                                                     u16* __restrict__ dst,
                                                     int R, int Cn) {
  __shared__ float tile[32][33];
  const int tx = threadIdx.x, ty = threadIdx.y;
  const int c0 = blockIdx.x * 32, r0 = blockIdx.y * 32;
#pragma unroll
  for (int i = 0; i < 4; ++i)
    tile[ty + i * 8][tx] = src[(size_t)(r0 + ty + i * 8) * Cn + c0 + tx];
  __syncthreads();
#pragma unroll
  for (int i = 0; i < 4; ++i)
    dst[(size_t)(c0 + ty + i * 8) * R + r0 + tx] = f2bf(tile[tx][ty + i * 8]);
}

// ---- FFN weight transpose with gate/up interleave: src[2048][5632] f32 ->
// dst row' = (n>>7)*256 + base + (n&127), i.e. per 128-col chunk: gate rows
// then up rows, so gemm_ffn's 256-row B-block covers one output chunk. ----
__global__ __launch_bounds__(256) void transpose_cvt_ffn(const float* __restrict__ src,
                                                         u16* __restrict__ dst,
                                                         int base) {
  __shared__ float tile[32][33];
  const int tx = threadIdx.x, ty = threadIdx.y;
  const int c0 = blockIdx.x * 32, r0 = blockIdx.y * 32;  // c0 over 5632, r0 over 2048
#pragma unroll
  for (int i = 0; i < 4; ++i)
    tile[ty + i * 8][tx] = src[(size_t)(r0 + ty + i * 8) * HIDQ + c0 + tx];
  __syncthreads();
#pragma unroll
  for (int i = 0; i < 4; ++i) {
    const int n = c0 + ty + i * 8;
    const int row = (n >> 7) * 256 + base + (n & 127);
    dst[(size_t)row * DIMQ + r0 + tx] = f2bf(tile[tx][ty + i * 8]);
  }
}

// ---- V transpose: qkv v-slice [s][d] bf16 -> Vt[bh][d][s] bf16 ----
__global__ __launch_bounds__(256) void vtrans_k(const u16* __restrict__ qkv,
                                                u16* __restrict__ vt) {
  __shared__ u16 tile[32][33];
  const int bh = blockIdx.z;
  const int b = bh >> 4, h = bh & 15;
  const int s0 = blockIdx.x * 32, d0 = blockIdx.y * 32;
  const int tx = threadIdx.x, ty = threadIdx.y;
  const u16* src = qkv + (size_t)(b * SQ) * 6144 + 4096 + h * HDQ;
#pragma unroll
  for (int i = 0; i < 4; ++i)
    tile[ty + i * 8][tx] = src[(size_t)(s0 + ty + i * 8) * 6144 + d0 + tx];
  __syncthreads();
  u16* dst = vt + (size_t)bh * HDQ * SQ;
#pragma unroll
  for (int i = 0; i < 4; ++i)
    dst[(size_t)(d0 + ty + i * 8) * SQ + s0 + tx] = tile[tx][ty + i * 8];
}

// ---- RMSNorm: f32 [rows][2048] -> bf16, one block per row ----
__global__ __launch_bounds__(256) void rmsnorm_k(const float* __restrict__ x,
                                                 const float* __restrict__ w,
                                                 u16* __restrict__ o) {
  const int row = blockIdx.x;
  const int t = threadIdx.x;
  const float* xr = x + (size_t)row * DIMQ;
  const float4 a = ((const float4*)xr)[t * 2];
  const float4 b = ((const float4*)xr)[t * 2 + 1];
  float ss = a.x * a.x + a.y * a.y + a.z * a.z + a.w * a.w +
             b.x * b.x + b.y * b.y + b.z * b.z + b.w * b.w;
#pragma unroll
  for (int off = 32; off > 0; off >>= 1) ss += __shfl_down(ss, off);
  __shared__ float red[4];
  if ((t & 63) == 0) red[t >> 6] = ss;
  __syncthreads();
  ss = red[0] + red[1] + red[2] + red[3];
  const float rs = rsqrtf(ss * (1.0f / (float)DIMQ) + 1e-6f);
  const float4 wa = ((const float4*)w)[t * 2];
  const float4 wb = ((const float4*)w)[t * 2 + 1];
  s16x8 ov;
  ov[0] = (short)f2bf(a.x * rs * wa.x);
  ov[1] = (short)f2bf(a.y * rs * wa.y);
  ov[2] = (short)f2bf(a.z * rs * wa.z);
  ov[3] = (short)f2bf(a.w * rs * wa.w);
  ov[4] = (short)f2bf(b.x * rs * wb.x);
  ov[5] = (short)f2bf(b.y * rs * wb.y);
  ov[6] = (short)f2bf(b.z * rs * wb.z);
  ov[7] = (short)f2bf(b.w * rs * wb.w);
  *(s16x8*)(o + (size_t)row * DIMQ + t * 8) = ov;
}

// ============================================================================
// 256xBN tile GEMM, BK=64, 8 waves, 4-phase interleaved schedule (round-3
// structure: (row&7)<<4 LDS swizzle both-sides, counted vmcnt(4), setprio,
// XCD-chunked row-major block order). Optional fused RoPE epilogue (qkv).
// ============================================================================
template <int OM, int BN, int ROPE>
__global__ __launch_bounds__(512, 1) void gemm256(const u16* __restrict__ A,
                                                  const u16* __restrict__ Bt,
                                                  u16* __restrict__ Cb,
                                                  float* __restrict__ Cf,
                                                  const float* __restrict__ resid,
                                                  const float* __restrict__ fc,
                                                  const float* __restrict__ fs,
                                                  int N, int K, int lda) {
  constexpr int BT = BN * 128;             // B K-tile bytes
  constexpr int BLB = BN / 128;            // gl_lds per thread per B half
  constexpr int WNv = (BN == 256) ? 4 : 2; // waves along N
  constexpr int MF = (BN == 256) ? 8 : 4;  // 16-row A frags per wave
  constexpr int MFH = MF / 2;
  __shared__ u16 lds[(65536 + 2 * BT) / 2];  // A: 0,32768; B: 65536, 65536+BT
  const int tid = threadIdx.x, wid = tid >> 6, lane = tid & 63;
  const int wm = wid / WNv, wn = wid % WNv;
  const int r = lane & 15, kc = lane >> 4;
  const int nbx = N / BN;
  const int nwg = nbx << 4;
  const int o = blockIdx.x;
  const int seq = (o & 7) * (nwg >> 3) + (o >> 3);  // XCD-chunked, row-major
  const int by = seq / nbx, bx = seq - by * nbx;
  const int m0 = by << 8, n0 = bx * BN;
  const int T = K >> 6;

  const u16* Ag = A + (size_t)m0 * lda;
  const u16* Bg = Bt + (size_t)n0 * K;

  // staging source swizzle (involution byte^=((byte>>7&7)<<4); linear LDS dest)
  const int pl = (tid * 16) ^ (((tid >> 3) & 7) << 4);
  const int prow = pl >> 7;           // = tid>>3, 0..63
  const int pcol = (pl & 127) >> 1;   // element offset within 64-elem row

  // read-side swizzled base: row r, k-chunk kc (XOR ks<<6 per k-slice)
  const int rd0 = r * 128 + ((kc * 16) ^ ((r & 7) << 4));
  const int waveA = wm * (MF * 2048);
  const int waveB = wn * 8192;

  f32x4 acc[MF][4] = {};
  s16x8 af[MFH][2], bfL[2][2], bfH[2][2];

#define STAGE_A(G, kt, BUFB, h)                                                   \
  {                                                                               \
    _Pragma("unroll") for (int i = 0; i < 2; ++i)                                 \
        gl_lds16(G + (size_t)((h) * 128 + i * 64 + prow) * lda + (kt) * 64 + pcol,\
                 (char*)lds + (BUFB) + (h) * 16384 + i * 8192 + (wid << 10));     \
  }
#define STAGE_B(G, kt, BUFB, h)                                                   \
  {                                                                               \
    _Pragma("unroll") for (int i = 0; i < BLB; ++i)                               \
        gl_lds16(G + (size_t)((h) * (BN / 2) + i * 64 + prow) * K + (kt) * 64 + pcol, \
                 (char*)lds + (BUFB) + (h) * (BT / 2) + i * 8192 + (wid << 10));  \
  }

  // prologue: tile0 A+B -> buf0; tile1 A -> buf1
  STAGE_A(Ag, 0, 0, 0);
  STAGE_A(Ag, 0, 0, 1);
  STAGE_B(Bg, 0, 65536, 0);
  STAGE_B(Bg, 0, 65536, 1);
  STAGE_A(Ag, 1, 32768, 0);
  STAGE_A(Ag, 1, 32768, 1);
  asm volatile("s_waitcnt vmcnt(4)" ::: "memory");
  SBAR();

#define TILE_BODY(t, cur)                                                         \
  {                                                                               \
    const int tp1 = ((t) + 1 < T) ? (t) + 1 : T - 1;                              \
    const int tp2 = ((t) + 2 < T) ? (t) + 2 : T - 1;                              \
    const int AB = (cur)*32768;                                                   \
    const int BB = 65536 + (cur)*BT;                                              \
    const int BBn = 65536 + (1 - (cur)) * BT;                                     \
    /* ---- phase 0: stage B.h0(t+1); read A(lo)+B(lo); mfma Q(0,0) ---- */       \
    STAGE_B(Bg, tp1, BBn, 0);                                                     \
    _Pragma("unroll") for (int j = 0; j < MFH; ++j)                               \
        _Pragma("unroll") for (int ks = 0; ks < 2; ++ks)                          \
            af[j][ks] = *(const s16x8*)((const char*)lds + AB + waveA +           \
                                        j * 2048 + (rd0 ^ (ks << 6)));            \
    _Pragma("unroll") for (int n = 0; n < 2; ++n)                                 \
        _Pragma("unroll") for (int ks = 0; ks < 2; ++ks)                          \
            bfL[n][ks] = *(const s16x8*)((const char*)lds + BB + waveB +          \
                                         n * 2048 + (rd0 ^ (ks << 6)));           \
    __builtin_amdgcn_s_setprio(1);                                                \
    _Pragma("unroll") for (int ks = 0; ks < 2; ++ks)                              \
        _Pragma("unroll") for (int j = 0; j < MFH; ++j)                           \
            _Pragma("unroll") for (int n = 0; n < 2; ++n)                         \
                acc[j][n] = mfma16(af[j][ks], bfL[n][ks], acc[j][n]);             \
    __builtin_amdgcn_s_setprio(0);                                                \
    /* ---- phase 1: stage B.h1(t+1); read B(hi); mfma Q(0,1) ---- */             \
    STAGE_B(Bg, tp1, BBn, 1);                                                     \
    _Pragma("unroll") for (int n = 0; n < 2; ++n)                                 \
        _Pragma("unroll") for (int ks = 0; ks < 2; ++ks)                          \
            bfH[n][ks] = *(const s16x8*)((const char*)lds + BB + waveB +          \
                                         (2 + n) * 2048 + (rd0 ^ (ks << 6)));     \
    __builtin_amdgcn_s_setprio(1);                                                \
    _Pragma("unroll") for (int ks = 0; ks < 2; ++ks)                              \
        _Pragma("unroll") for (int j = 0; j < MFH; ++j)                           \
            _Pragma("unroll") for (int n = 0; n < 2; ++n)                         \
                acc[j][2 + n] = mfma16(af[j][ks], bfH[n][ks], acc[j][2 + n]);     \
    __builtin_amdgcn_s_setprio(0);                                                \
    /* ---- phase 2: read A(hi); mfma Q(1,0) ---- */                              \
    _Pragma("unroll") for (int j = 0; j < MFH; ++j)                               \
        _Pragma("unroll") for (int ks = 0; ks < 2; ++ks)                          \
            af[j][ks] = *(const s16x8*)((const char*)lds + AB + waveA +           \
                                        (MFH + j) * 2048 + (rd0 ^ (ks << 6)));    \
    __builtin_amdgcn_s_setprio(1);                                                \
    _Pragma("unroll") for (int ks = 0; ks < 2; ++ks)                              \
        _Pragma("unroll") for (int j = 0; j < MFH; ++j)                           \
            _Pragma("unroll") for (int n = 0; n < 2; ++n)                         \
                acc[MFH + j][n] = mfma16(af[j][ks], bfL[n][ks], acc[MFH + j][n]); \
    __builtin_amdgcn_s_setprio(0);                                                \
    SBAR(); /* all reads of buf[cur] done -> safe to overwrite its A region */    \
    /* ---- phase 3: stage A(t+2) into buf[cur]; mfma Q(1,1) ---- */              \
    STAGE_A(Ag, tp2, AB, 0);                                                      \
    STAGE_A(Ag, tp2, AB, 1);                                                      \
    __builtin_amdgcn_s_setprio(1);                                                \
    _Pragma("unroll") for (int ks = 0; ks < 2; ++ks)                              \
        _Pragma("unroll") for (int j = 0; j < MFH; ++j)                           \
            _Pragma("unroll") for (int n = 0; n < 2; ++n)                         \
                acc[MFH + j][2 + n] = mfma16(af[j][ks], bfH[n][ks], acc[MFH + j][2 + n]); \
    __builtin_amdgcn_s_setprio(0);                                                \
    asm volatile("s_waitcnt vmcnt(4)" ::: "memory"); /* A(t+1)+B(t+1) landed */   \
    SBAR();                                                                       \
  }

  for (int tt = 0; tt < T; tt += 2) {  // T even for all shapes (32, 88)
    TILE_BODY(tt, 0);
    TILE_BODY(tt + 1, 1);
  }
#undef TILE_BODY
#undef STAGE_A
#undef STAGE_B

  const bool do_rope = ROPE && (n0 < 4096);
#pragma unroll
  for (int mf = 0; mf < MF; ++mf)
#pragma unroll
    for (int nf = 0; nf < 4; ++nf)
#pragma unroll
      for (int j = 0; j < 4; ++j) {
        const int rr = m0 + wm * (MF * 16) + mf * 16 + kc * 4 + j;
        const int cc = n0 + wn * 64 + nf * 16 + r;
        float v = acc[mf][nf][j];
        if (OM == 0) {
          if (ROPE) {  // fused RoPE: lanes r, r^1 hold (re,im) of one pair
            const float partner = __shfl_xor(v, 1);
            if (do_rope) {
              const int s = rr & (SQ - 1);
              const int i0 = (cc >> 1) & 63;
              const float cv = fc[s * 64 + i0];
              const float sv = fs[s * 64 + i0];
              v = ((r & 1) == 0) ? v * cv - partner * sv : v * cv + partner * sv;
            }
          }
          Cb[(size_t)rr * N + cc] = f2bf(v);
        } else {
          Cf[(size_t)rr * N + cc] = v + resid[(size_t)rr * N + cc];
        }
      }
}

// ============================================================================
// Fused FFN GEMM: act[4096][5632] = silu(f_in@w1) * (f_in@w3), bf16 out.
// B = interleaved w13i: per 128-col chunk c, rows [256c..256c+127] = w1T,
// rows [256c+128..256c+255] = w3T. Tile: 256 m x 128 out-cols, BK=64,
// 8 waves = 4 wm x 2 wn; each wave holds gate AND up 64x64 accumulators.
// ============================================================================
__global__ __launch_bounds__(512, 1) void gemm_ffn(const u16* __restrict__ A,
                                                   const u16* __restrict__ Bi,
                                                   u16* __restrict__ act) {
  __shared__ u16 lds[65536];  // A bufs @0,32768; B bufs @65536,98304 (bytes)
  const int tid = threadIdx.x, wid = tid >> 6, lane = tid & 63;
  const int wm = wid >> 1, wn = wid & 1;
  const int r = lane & 15, kc = lane >> 4;
  const int o = blockIdx.x;                 // 704 blocks = 16 m x 44 chunks
  const int seq = (o & 7) * 88 + (o >> 3);  // XCD-chunked, row-major
  const int by = seq / 44, bx = seq - by * 44;
  const int m0 = by << 8;
  const int T = 32;  // K = 2048

  const u16* Ag = A + (size_t)m0 * DIMQ;
  const u16* Bg = Bi + (size_t)bx * 256 * DIMQ;

  const int pl = (tid * 16) ^ (((tid >> 3) & 7) << 4);
  const int prow = pl >> 7, pcol = (pl & 127) >> 1;
  const int rd0 = r * 128 + ((kc * 16) ^ ((r & 7) << 4));
  const int waveA = wm * 8192;  // 64 rows
  const int waveB = wn * 8192;  // 64 gate rows (up at +16384)

  f32x4 accG[4][4] = {}, accU[4][4] = {};
  s16x8 af[4][2], bL[2][2], bH[2][2];

#define STG(G, kt, BUFB, h)                                                       \
  {                                                                               \
    _Pragma("unroll") for (int i = 0; i < 2; ++i)                                 \
        gl_lds16(G + (size_t)((h) * 128 + i * 64 + prow) * DIMQ + (kt) * 64 + pcol,\
                 (char*)lds + (BUFB) + (h) * 16384 + i * 8192 + (wid << 10));     \
  }

  STG(Ag, 0, 0, 0);
  STG(Ag, 0, 0, 1);
  STG(Bg, 0, 65536, 0);
  STG(Bg, 0, 65536, 1);
  STG(Ag, 1, 32768, 0);
  STG(Ag, 1, 32768, 1);
  asm volatile("s_waitcnt vmcnt(4)" ::: "memory");
  SBAR();

#define FFN_BODY(t, cur)                                                          \
  {                                                                               \
    const int tp1 = ((t) + 1 < T) ? (t) + 1 : T - 1;                              \
    const int tp2 = ((t) + 2 < T) ? (t) + 2 : T - 1;                              \
    const int AB = (cur)*32768;                                                   \
    const int BB = 65536 + (cur)*32768;                                           \
    const int BBn = 65536 + (1 - (cur)) * 32768;                                  \
    /* ph0: stage B.h0(t+1); read af + gate01; mfma G01 */                        \
    STG(Bg, tp1, BBn, 0);                                                         \
    _Pragma("unroll") for (int j = 0; j < 4; ++j)                                 \
        _Pragma("unroll") for (int ks = 0; ks < 2; ++ks)                          \
            af[j][ks] = *(const s16x8*)((const char*)lds + AB + waveA +           \
                                        j * 2048 + (rd0 ^ (ks << 6)));            \
    _Pragma("unroll") for (int n = 0; n < 2; ++n)                                 \
        _Pragma("unroll") for (int ks = 0; ks < 2; ++ks)                          \
            bL[n][ks] = *(const s16x8*)((const char*)lds + BB + waveB +           \
                                        n * 2048 + (rd0 ^ (ks << 6)));            \
    __builtin_amdgcn_s_setprio(1);                                                \
    _Pragma("unroll") for (int ks = 0; ks < 2; ++ks)                              \
        _Pragma("unroll") for (int j = 0; j < 4; ++j)                             \
            _Pragma("unroll") for (int n = 0; n < 2; ++n)                         \
                accG[j][n] = mfma16(af[j][ks], bL[n][ks], accG[j][n]);            \
    __builtin_amdgcn_s_setprio(0);                                                \
    /* ph1: stage B.h1(t+1); read gate23; mfma G23 */                             \
    STG(Bg, tp1, BBn, 1);                                                         \
    _Pragma("unroll") for (int n = 0; n < 2; ++n)                                 \
        _Pragma("unroll") for (int ks = 0; ks < 2; ++ks)                          \
            bH[n][ks] = *(const s16x8*)((const char*)lds + BB + waveB +           \
                                        (2 + n) * 2048 + (rd0 ^ (ks << 6)));      \
    __builtin_amdgcn_s_setprio(1);                                                \
    _Pragma("unroll") for (int ks = 0; ks < 2; ++ks)                              \
        _Pragma("unroll") for (int j = 0; j < 4; ++j)                             \
            _Pragma("unroll") for (int n = 0; n < 2; ++n)                         \
                accG[j][2 + n] = mfma16(af[j][ks], bH[n][ks], accG[j][2 + n]);    \
    __builtin_amdgcn_s_setprio(0);                                                \
    /* ph2: read up01; mfma U01 */                                                \
    _Pragma("unroll") for (int n = 0; n < 2; ++n)                                 \
        _Pragma("unroll") for (int ks = 0; ks < 2; ++ks)                          \
            bL[n][ks] = *(const s16x8*)((const char*)lds + BB + 16384 + waveB +   \
                                        n * 2048 + (rd0 ^ (ks << 6)));            \
    __builtin_amdgcn_s_setprio(1);                                                \
    _Pragma("unroll") for (int ks = 0; ks < 2; ++ks)                              \
        _Pragma("unroll") for (int j = 0; j < 4; ++j)                             \
            _Pragma("unroll") for (int n = 0; n < 2; ++n)                         \
                accU[j][n] = mfma16(af[j][ks], bL[n][ks], accU[j][n]);            \
    __builtin_amdgcn_s_setprio(0);                                                \
    /* ph2b: read up23 (B-buf: not touched by STAGE_A, may cross barrier) */      \
    _Pragma("unroll") for (int n = 0; n < 2; ++n)                                 \
        _Pragma("unroll") for (int ks = 0; ks < 2; ++ks)                          \
            bH[n][ks] = *(const s16x8*)((const char*)lds + BB + 16384 + waveB +   \
                                        (2 + n) * 2048 + (rd0 ^ (ks << 6)));      \
    SBAR(); /* all A-buf reads done -> safe to overwrite */                       \
    /* ph3: stage A(t+2); mfma U23 */                                             \
    STG(Ag, tp2, AB, 0);                                                          \
    STG(Ag, tp2, AB, 1);                                                          \
    __builtin_amdgcn_s_setprio(1);                                                \
    _Pragma("unroll") for (int ks = 0; ks < 2; ++ks)                              \
        _Pragma("unroll") for (int j = 0; j < 4; ++j)                             \
            _Pragma("unroll") for (int n = 0; n < 2; ++n)                         \
                accU[j][2 + n] = mfma16(af[j][ks], bH[n][ks], accU[j][2 + n]);    \
    __builtin_amdgcn_s_setprio(0);                                                \
    asm volatile("s_waitcnt vmcnt(4)" ::: "memory");                              \
    SBAR();                                                                       \
  }

  for (int tt = 0; tt < T; tt += 2) {
    FFN_BODY(tt, 0);
    FFN_BODY(tt + 1, 1);
  }
#undef FFN_BODY
#undef STG

  const int cbase = bx * 128 + wn * 64;
#pragma unroll
  for (int mf = 0; mf < 4; ++mf)
#pragma unroll
    for (int nf = 0; nf < 4; ++nf)
#pragma unroll
      for (int j = 0; j < 4; ++j) {
        const int rr = m0 + wm * 64 + mf * 16 + kc * 4 + j;
        const int cc = cbase + nf * 16 + r;
        const float g = accG[mf][nf][j];
        const float u = accU[mf][nf][j];
        const float a = g / (1.f + __expf(-g)) * u;
        act[(size_t)rr * HIDQ + cc] = f2bf(a);
      }
}

// ---- causal flash attention. grid (bh=32, qtrev=32), 4 waves, 16 q-rows/wave ----
__global__ __launch_bounds__(256) void attn_k(const u16* __restrict__ qkv,
                                              const u16* __restrict__ vt,
                                              u16* __restrict__ outb) {
  __shared__ u16 Kl[64 * 136];      // [key][d], stride 136
  __shared__ u16 Vl[128 * 72];      // [d][key], stride 72
  __shared__ u16 Pl[4][16 * 80];    // per-wave P tile [qrow][key]
  const int bh = blockIdx.x;
  const int qt = 31 - blockIdx.y;    // heavy blocks dispatched first
  const int b = bh >> 4, h = bh & 15;
  const int q0 = qt * 64;
  const int tid = threadIdx.x, wid = tid >> 6, lane = tid & 63;
  const int r = lane & 15, kc = lane >> 4;
  const size_t base = (size_t)b * SQ * 6144;
  const u16* vtb = vt + (size_t)bh * HDQ * SQ;
  s16x8 qf[4];
  {
    const size_t qoff = base + (size_t)(q0 + wid * 16 + r) * 6144 + h * HDQ;
#pragma unroll
    for (int kk = 0; kk < 4; ++kk)
      qf[kk] = *(const s16x8*)&qkv[qoff + kk * 32 + kc * 8];
  }
  f32x4 acc_o[8] = {};
  float m_run[4], l_run[4];
#pragma unroll
  for (int j = 0; j < 4; ++j) { m_run[j] = -1e30f; l_run[j] = 0.f; }
  const int nt = qt + 1;
  const int skey = tid >> 2, sseg = (tid & 3) * 32;   // K staging: 64 keys x 4 segs
  const int vd = tid >> 1, vseg = (tid & 1) * 32;     // V staging: 128 d x 2 segs
  for (int t = 0; t < nt; ++t) {
    const int kv0 = t * 64;
    __syncthreads();
    {  // stage K [64][136] and V^T [128][72], all b128
      const u16* kg = &qkv[base + (size_t)(kv0 + skey) * 6144 + 2048 + h * HDQ + sseg];
      const u16* vg = &vtb[(size_t)vd * SQ + kv0 + vseg];
#pragma unroll
      for (int jj = 0; jj < 4; ++jj)
        *(s16x8*)&Kl[skey * 136 + sseg + jj * 8] = *(const s16x8*)(kg + jj * 8);
#pragma unroll
      for (int jj = 0; jj < 4; ++jj)
        *(s16x8*)&Vl[vd * 72 + vseg + jj * 8] = *(const s16x8*)(vg + jj * 8);
    }
    __syncthreads();
    // S = Q*K^T for this wave's 16 q-rows x 64 keys
    f32x4 sacc[4] = {};
#pragma unroll
    for (int nf = 0; nf < 4; ++nf)
#pragma unroll
      for (int kk = 0; kk < 4; ++kk) {
        const s16x8 kf = *(const s16x8*)&Kl[(nf * 16 + r) * 136 + kk * 32 + kc * 8];
        sacc[nf] = mfma16(qf[kk], kf, sacc[nf]);
      }
    // online softmax (rows j are spread over 16-lane groups; reduce via shfl_xor)
    float p[4][4], alpha[4];
#pragma unroll
    for (int j = 0; j < 4; ++j) {
      const int qrow = q0 + wid * 16 + kc * 4 + j;
      float svs[4];
      float tm = -1e30f;
#pragma unroll
      for (int nf = 0; nf < 4; ++nf) {
        const int key = kv0 + nf * 16 + r;
        float sv = sacc[nf][j] * SC_ATTN;
        sv = (key > qrow) ? -1e30f : sv;
        svs[nf] = sv;
        tm = fmaxf(tm, sv);
      }
      tm = fmaxf(tm, __shfl_xor(tm, 1));
      tm = fmaxf(tm, __shfl_xor(tm, 2));
      tm = fmaxf(tm, __shfl_xor(tm, 4));
      tm = fmaxf(tm, __shfl_xor(tm, 8));
      const float mnew = fmaxf(m_run[j], tm);
      alpha[j] = __expf(m_run[j] - mnew);
      m_run[j] = mnew;
      float rs = 0.f;
#pragma unroll
      for (int nf = 0; nf < 4; ++nf) {
        const float pv = __expf(svs[nf] - mnew);
        p[nf][j] = pv;
        rs += pv;
      }
      rs += __shfl_xor(rs, 1);
      rs += __shfl_xor(rs, 2);
      rs += __shfl_xor(rs, 4);
      rs += __shfl_xor(rs, 8);
      l_run[j] = l_run[j] * alpha[j] + rs;
    }
#pragma unroll
    for (int nf = 0; nf < 8; ++nf)
#pragma unroll
      for (int j = 0; j < 4; ++j)
        acc_o[nf][j] *= alpha[j];
    // P (D-layout) -> LDS -> A-layout fragments
#pragma unroll
    for (int nf = 0; nf < 4; ++nf)
#pragma unroll
      for (int j = 0; j < 4; ++j)
        Pl[wid][(kc * 4 + j) * 80 + nf * 16 + r] = f2bf(p[nf][j]);
#pragma unroll
    for (int ks = 0; ks < 2; ++ks) {
      const s16x8 pa = *(const s16x8*)&Pl[wid][r * 80 + ks * 32 + kc * 8];
#pragma unroll
      for (int nf = 0; nf < 8; ++nf) {
        const s16x8 bv = *(const s16x8*)&Vl[(nf * 16 + r) * 72 + ks * 32 + kc * 8];
        acc_o[nf] = mfma16(pa, bv, acc_o[nf]);
      }
    }
  }
#pragma unroll
  for (int j = 0; j < 4; ++j) {
    const float inv = 1.0f / l_run[j];
    const size_t orow = (size_t)(b * SQ + q0 + wid * 16 + kc * 4 + j) * DIMQ + h * HDQ;
#pragma unroll
    for (int nf = 0; nf < 8; ++nf)
      outb[orow + nf * 16 + r] = f2bf(acc_o[nf][j] * inv);
  }
}

extern "C" void kernel_launch(void* const* d_in, const int* in_sizes, int n_in,
                              void* d_out, int out_size, void* d_ws, size_t ws_size,
                              hipStream_t stream) {
  const float* x   = (const float*)d_in[0];
  const float* wq  = (const float*)d_in[1];
  const float* wk  = (const float*)d_in[2];
  const float* wv  = (const float*)d_in[3];
  const float* wo  = (const float*)d_in[4];
  const float* w1  = (const float*)d_in[5];
  const float* w2  = (const float*)d_in[6];  // note: w2 comes before w3 in dict order
  const float* w3  = (const float*)d_in[7];
  const float* anw = (const float*)d_in[8];
  const float* fnw = (const float*)d_in[9];
  const float* fc  = (const float*)d_in[10];
  const float* fs  = (const float*)d_in[11];
  float* out = (float*)d_out;

  char* ws = (char*)d_ws;
  // weights (bf16, transposed)
  u16* wqkvT = (u16*)(ws);                                  // [6144][2048]
  u16* woT   = (u16*)(ws + 25165824);                       // [2048][2048]
  u16* w13i  = (u16*)(ws + 25165824 + 8388608);             // [11264][2048] interleaved
  u16* w2T   = (u16*)(ws + 25165824 + 8388608 + 46137344);  // [2048][5632]
  // activations
  u16* hin   = (u16*)(ws + 102760448);                      // [4096][2048] bf16
  u16* qkvb  = (u16*)(ws + 119537664);                      // attn: [4096][6144]; FFN: act [4096][5632]
  u16* act   = qkvb;
  u16* attnb = (u16*)(ws + 119537664 + 50331648);           // [4096][2048] bf16
  u16* vtb   = (u16*)(ws + 119537664 + 50331648 + 16777216);// [32][128][2048] bf16
  float* h = out;                                           // h lives in d_out

  const dim3 tb(32, 8);
  transpose_cvt<<<dim3(64, 64), tb, 0, stream>>>(wq, wqkvT, 2048, 2048);
  transpose_cvt<<<dim3(64, 64), tb, 0, stream>>>(wk, wqkvT + (size_t)2048 * 2048, 2048, 2048);
  transpose_cvt<<<dim3(64, 64), tb, 0, stream>>>(wv, wqkvT + (size_t)2 * 2048 * 2048, 2048, 2048);
  transpose_cvt<<<dim3(64, 64), tb, 0, stream>>>(wo, woT, 2048, 2048);
  transpose_cvt_ffn<<<dim3(176, 64), tb, 0, stream>>>(w1, w13i, 0);
  transpose_cvt_ffn<<<dim3(176, 64), tb, 0, stream>>>(w3, w13i, 128);
  transpose_cvt<<<dim3(64, 176), tb, 0, stream>>>(w2, w2T, 5632, 2048);

  rmsnorm_k<<<4096, 256, 0, stream>>>(x, anw, hin);
  gemm256<0, 128, 1><<<768, 512, 0, stream>>>(hin, wqkvT, qkvb, nullptr, nullptr, fc, fs, 6144, 2048, 2048);
  vtrans_k<<<dim3(64, 4, 32), tb, 0, stream>>>(qkvb, vtb);
  attn_k<<<dim3(32, 32), 256, 0, stream>>>(qkvb, vtb, attnb);
  gemm256<1, 128, 0><<<256, 512, 0, stream>>>(attnb, woT, nullptr, h, x, nullptr, nullptr, 2048, 2048, 2048);
  rmsnorm_k<<<4096, 256, 0, stream>>>(h, fnw, hin);
  gemm_ffn<<<704, 512, 0, stream>>>(hin, w13i, act);
  gemm256<1, 128, 0><<<256, 512, 0, stream>>>(act, w2T, nullptr, out, h, nullptr, nullptr, 2048, 5632, 5632);
}